// Round 1
// baseline (380.453 us; speedup 1.0000x reference)
//
#include <hip/hip_runtime.h>
#include <hip/hip_bf16.h>

// Problem: out[e] = relu(concat(emb[src[e]], emb[dst[e]]) @ w1 + b1) @ w2
//   emb: 100000x128 f32, train_sample: 300000x2 int (32 or 64), w1: 256x64,
//   b1: 64, w2: 64x1. Output: 300000 f32.
//
// Restructure: P[n][c] = emb[n] . w1[0:128, c]   + b1[c]   (c < 64)
//              P[n][64+c] = emb[n] . w1[128:256, c]        (c < 64)
// Then out[e] = sum_j relu(P[src][j] + P[dst][64+j]) * w2[j].

#define D_FEAT 128
#define HIDDEN 64

// ---------------------------------------------------------------------------
// Detect whether train_sample is int64 (little-endian: odd int32 words all 0
// since indices < 100000) or int32. Writes 1 (int64) / 0 (int32) to *flag.
__global__ void detect_idx_kernel(const int* __restrict__ ts32, int* __restrict__ flag) {
    if (threadIdx.x == 0 && blockIdx.x == 0) {
        int is64 = 1;
        for (int i = 1; i < 64; i += 2) {
            if (ts32[i] != 0) { is64 = 0; break; }
        }
        *flag = is64;
    }
}

// ---------------------------------------------------------------------------
// Precompute P (n_nodes x 128). Block = 256 threads = 4 waves.
// wave -> (node slot 0/1, column half 0/1). Lane j handles column half*64+j.
// Each thread keeps its 128-entry weight column in registers (static unroll).
__global__ void __launch_bounds__(256)
precompute_kernel(const float* __restrict__ emb, const float* __restrict__ w1,
                  const float* __restrict__ b1, float* __restrict__ P, int n_nodes) {
    const int lane = threadIdx.x & 63;
    const int wid  = threadIdx.x >> 6;   // 0..3
    const int half = wid & 1;            // 0: cols 0..63 (A+bias), 1: cols 64..127 (B)
    const int slot = wid >> 1;           // 0..1
    const int c    = half * 64 + lane;

    float w[128];
#pragma unroll
    for (int k = 0; k < 128; ++k) {
        // half==0: w1[k][lane]; half==1: w1[128+k][lane]  (w1 is 256x64 row-major)
        w[k] = w1[(half * 128 + k) * 64 + lane];
    }
    const float bias = half ? 0.0f : b1[lane];

    for (long long n = (long long)blockIdx.x * 2 + slot; n < n_nodes;
         n += (long long)gridDim.x * 2) {
        const float4* row4 = reinterpret_cast<const float4*>(emb + n * D_FEAT);
        float acc = bias;
#pragma unroll
        for (int k4 = 0; k4 < 32; ++k4) {
            float4 r = row4[k4];   // same addr across 64 lanes -> broadcast
            acc += r.x * w[4 * k4 + 0];
            acc += r.y * w[4 * k4 + 1];
            acc += r.z * w[4 * k4 + 2];
            acc += r.w * w[4 * k4 + 3];
        }
        P[n * 128 + c] = acc;
    }
}

// ---------------------------------------------------------------------------
// Edge pass: one wave per edge (grid-stride). Lane j = hidden unit j.
// Coalesced 256B reads of P[src][0:64] and P[dst][64:128].
__global__ void __launch_bounds__(256)
edge_kernel(const float* __restrict__ P, const void* __restrict__ ts,
            const int* __restrict__ flag, const float* __restrict__ w2,
            float* __restrict__ out, int n_edges) {
    const int lane = threadIdx.x & 63;
    const int gw   = blockIdx.x * (blockDim.x >> 6) + (threadIdx.x >> 6);
    const int nw   = gridDim.x * (blockDim.x >> 6);
    const float w2v = w2[lane];
    const bool is64 = flag ? (*flag != 0) : false;
    const int* ts32 = (const int*)ts;
    const long long* ts64 = (const long long*)ts;

    for (int e = gw; e < n_edges; e += nw) {
        long long s, d;
        if (is64) { s = ts64[2 * e]; d = ts64[2 * e + 1]; }
        else      { s = ts32[2 * e]; d = ts32[2 * e + 1]; }
        float a = P[s * 128 + lane];
        float b = P[d * 128 + 64 + lane];
        float h = a + b;
        h = h > 0.0f ? h : 0.0f;
        float v = h * w2v;
#pragma unroll
        for (int off = 32; off > 0; off >>= 1) v += __shfl_xor(v, off);
        if (lane == 0) out[e] = v;
    }
}

// ---------------------------------------------------------------------------
// Fallback (only if ws too small for P): fused gather + MLP, wave per edge.
__global__ void __launch_bounds__(256)
direct_kernel(const float* __restrict__ emb, const void* __restrict__ ts,
              const int* __restrict__ flag, const float* __restrict__ w1,
              const float* __restrict__ b1, const float* __restrict__ w2,
              float* __restrict__ out, int n_edges) {
    const int lane = threadIdx.x & 63;
    const int gw   = blockIdx.x * (blockDim.x >> 6) + (threadIdx.x >> 6);
    const int nw   = gridDim.x * (blockDim.x >> 6);
    const float w2v  = w2[lane];
    const float bias = b1[lane];
    const bool is64 = flag ? (*flag != 0) : false;
    const int* ts32 = (const int*)ts;
    const long long* ts64 = (const long long*)ts;

    for (int e = gw; e < n_edges; e += nw) {
        long long s, d;
        if (is64) { s = ts64[2 * e]; d = ts64[2 * e + 1]; }
        else      { s = ts32[2 * e]; d = ts32[2 * e + 1]; }
        const float4* s4 = reinterpret_cast<const float4*>(emb + s * D_FEAT);
        const float4* d4 = reinterpret_cast<const float4*>(emb + d * D_FEAT);
        float acc = bias;
#pragma unroll
        for (int k4 = 0; k4 < 32; ++k4) {
            float4 r = s4[k4];
            acc += r.x * w1[(4 * k4 + 0) * 64 + lane];
            acc += r.y * w1[(4 * k4 + 1) * 64 + lane];
            acc += r.z * w1[(4 * k4 + 2) * 64 + lane];
            acc += r.w * w1[(4 * k4 + 3) * 64 + lane];
        }
#pragma unroll
        for (int k4 = 0; k4 < 32; ++k4) {
            float4 r = d4[k4];
            acc += r.x * w1[(128 + 4 * k4 + 0) * 64 + lane];
            acc += r.y * w1[(128 + 4 * k4 + 1) * 64 + lane];
            acc += r.z * w1[(128 + 4 * k4 + 2) * 64 + lane];
            acc += r.w * w1[(128 + 4 * k4 + 3) * 64 + lane];
        }
        float h = acc > 0.0f ? acc : 0.0f;
        float v = h * w2v;
#pragma unroll
        for (int off = 32; off > 0; off >>= 1) v += __shfl_xor(v, off);
        if (lane == 0) out[e] = v;
    }
}

// ---------------------------------------------------------------------------
extern "C" void kernel_launch(void* const* d_in, const int* in_sizes, int n_in,
                              void* d_out, int out_size, void* d_ws, size_t ws_size,
                              hipStream_t stream) {
    const float* emb = (const float*)d_in[0];
    const void*  ts  = d_in[1];
    const float* w1  = (const float*)d_in[2];
    const float* b1  = (const float*)d_in[3];
    const float* w2  = (const float*)d_in[4];
    float* out = (float*)d_out;

    const int n_nodes = in_sizes[0] / D_FEAT;   // 100000
    const int n_edges = in_sizes[1] / 2;        // 300000

    const size_t p_offset = 256;
    const size_t p_bytes  = (size_t)n_nodes * 128 * sizeof(float);
    const bool have_flag = ws_size >= sizeof(int);
    int* flag = have_flag ? (int*)d_ws : nullptr;

    if (have_flag) {
        detect_idx_kernel<<<1, 64, 0, stream>>>((const int*)ts, flag);
    }

    if (ws_size >= p_offset + p_bytes) {
        float* P = (float*)((char*)d_ws + p_offset);
        precompute_kernel<<<1024, 256, 0, stream>>>(emb, w1, b1, P, n_nodes);
        edge_kernel<<<2048, 256, 0, stream>>>(P, ts, flag, w2, out, n_edges);
    } else {
        direct_kernel<<<2048, 256, 0, stream>>>(emb, ts, flag, w1, b1, w2, out, n_edges);
    }
}

// Round 2
// 95.936 us; speedup vs baseline: 3.9657x; 3.9657x over previous
//
#include <hip/hip_runtime.h>
#include <hip/hip_bf16.h>

// Problem: out[e] = relu(concat(emb[src[e]], emb[dst[e]]) @ w1 + b1) @ w2
//   emb: 100000x128 f32, train_sample: 300000x2 int (32 or 64), w1: 256x64,
//   b1: 64, w2: 64x1. Output: 300000 f32.
//
// Restructure: P[n][j]   = emb[n] . w1[0:128, j]            (j <  64)
//              P[n][64+j] = emb[n] . w1[128:256, j]          (j <  64)
// (bias folded into P's first half)
// Then out[e] = sum_j relu(P[src][j] + P[dst][64+j]) * w2[j].

#define D_FEAT 128
#define HIDDEN 64

// ---------------------------------------------------------------------------
// Detect whether train_sample is int64 (little-endian: odd int32 words all 0
// since indices < 100000) or int32. Writes 1 (int64) / 0 (int32) to *flag.
__global__ void detect_idx_kernel(const int* __restrict__ ts32, int* __restrict__ flag) {
    if (threadIdx.x == 0 && blockIdx.x == 0) {
        int is64 = 1;
        for (int i = 1; i < 64; i += 2) {
            if (ts32[i] != 0) { is64 = 0; break; }
        }
        *flag = is64;
    }
}

// ---------------------------------------------------------------------------
// Precompute P (n_nodes x 128) = emb (n x 128) @ w_eff (128 x 128), + bias on
// first 64 cols. Tiled f32 GEMM: block = 256 threads, tile 128 nodes x 128
// cols, K chunked by 32. Per-thread micro-tile 8x8 (nodes nb..nb+3 &
// nb+64..nb+67, cols cb..cb+3 & cb+64..cb+67) so ds_read_b128 rows are
// contiguous across lanes -> <=2-way bank aliasing (free).
__global__ void __launch_bounds__(256)
precompute_kernel(const float* __restrict__ emb, const float* __restrict__ w1,
                  const float* __restrict__ b1, float* __restrict__ P, int n_nodes) {
    const int t  = threadIdx.x;
    const int n0 = blockIdx.x * 128;

    __shared__ float eS[32][128];   // [k'][node]  (transposed from global)
    __shared__ float wS[32][128];   // [k'][col]

    const int nb = (t & 15) * 4;    // node base within tile (second group +64)
    const int cb = (t >> 4) * 4;    // col base within tile  (second group +64)

    float acc[8][8];
#pragma unroll
    for (int i = 0; i < 8; ++i)
#pragma unroll
        for (int j = 0; j < 8; ++j) acc[i][j] = 0.0f;

    for (int kc = 0; kc < 4; ++kc) {
        const int k0 = kc * 32;

        // ---- stage eS (transpose): thread t loads 2 float4 of k for one node
        {
            const int nloc = t >> 2;        // 0..63
            const int kq   = (t & 3) * 8;   // 0,8,16,24
#pragma unroll
            for (int h = 0; h < 2; ++h) {
                const int node = n0 + h * 64 + nloc;
                float4 r0, r1;
                if (node < n_nodes) {
                    const float4* src = reinterpret_cast<const float4*>(
                        emb + (size_t)node * D_FEAT + k0 + kq);
                    r0 = src[0]; r1 = src[1];
                } else {
                    r0 = make_float4(0.f, 0.f, 0.f, 0.f);
                    r1 = r0;
                }
                const int nn = h * 64 + nloc;
                eS[kq + 0][nn] = r0.x; eS[kq + 1][nn] = r0.y;
                eS[kq + 2][nn] = r0.z; eS[kq + 3][nn] = r0.w;
                eS[kq + 4][nn] = r1.x; eS[kq + 5][nn] = r1.y;
                eS[kq + 6][nn] = r1.z; eS[kq + 7][nn] = r1.w;
            }
        }

        // ---- stage wS: w_eff[k][j] = j<64 ? w1[k][j] : w1[128+k][j-64]
        {
            const int kp = t >> 3;          // 0..31
            const int jg = t & 7;           // 0..7, 16 cols each
            const float* srcrow = (jg < 4)
                ? (w1 + (size_t)(k0 + kp) * 64 + jg * 16)
                : (w1 + (size_t)(128 + k0 + kp) * 64 + (jg - 4) * 16);
            const float4* s4 = reinterpret_cast<const float4*>(srcrow);
            float4 a = s4[0], b = s4[1], c = s4[2], d = s4[3];
            float* dst = &wS[kp][jg * 16];
            reinterpret_cast<float4*>(dst)[0] = a;
            reinterpret_cast<float4*>(dst)[1] = b;
            reinterpret_cast<float4*>(dst)[2] = c;
            reinterpret_cast<float4*>(dst)[3] = d;
        }
        __syncthreads();

        // ---- inner product over this K chunk
#pragma unroll
        for (int k = 0; k < 32; ++k) {
            float e[8], w[8];
            *reinterpret_cast<float4*>(&e[0]) =
                *reinterpret_cast<const float4*>(&eS[k][nb]);
            *reinterpret_cast<float4*>(&e[4]) =
                *reinterpret_cast<const float4*>(&eS[k][nb + 64]);
            *reinterpret_cast<float4*>(&w[0]) =
                *reinterpret_cast<const float4*>(&wS[k][cb]);
            *reinterpret_cast<float4*>(&w[4]) =
                *reinterpret_cast<const float4*>(&wS[k][cb + 64]);
#pragma unroll
            for (int i = 0; i < 8; ++i)
#pragma unroll
                for (int j = 0; j < 8; ++j)
                    acc[i][j] += e[i] * w[j];
        }
        __syncthreads();
    }

    // ---- epilogue: bias on first 64 cols, store
    float bias0[4];
#pragma unroll
    for (int jj = 0; jj < 4; ++jj) bias0[jj] = b1[cb + jj];

#pragma unroll
    for (int i = 0; i < 8; ++i) {
        const int node = n0 + ((i < 4) ? (nb + i) : (64 + nb + (i - 4)));
        if (node < n_nodes) {
            float4 o0, o1;
            o0.x = acc[i][0] + bias0[0]; o0.y = acc[i][1] + bias0[1];
            o0.z = acc[i][2] + bias0[2]; o0.w = acc[i][3] + bias0[3];
            o1.x = acc[i][4]; o1.y = acc[i][5];
            o1.z = acc[i][6]; o1.w = acc[i][7];
            *reinterpret_cast<float4*>(P + (size_t)node * 128 + cb) = o0;
            *reinterpret_cast<float4*>(P + (size_t)node * 128 + 64 + cb) = o1;
        }
    }
}

// ---------------------------------------------------------------------------
// Edge pass: one wave per edge (grid-stride). Lane j = hidden unit j.
// Coalesced 256B reads of P[src][0:64] and P[dst][64:128].
__global__ void __launch_bounds__(256)
edge_kernel(const float* __restrict__ P, const void* __restrict__ ts,
            const int* __restrict__ flag, const float* __restrict__ w2,
            float* __restrict__ out, int n_edges) {
    const int lane = threadIdx.x & 63;
    const int gw   = blockIdx.x * (blockDim.x >> 6) + (threadIdx.x >> 6);
    const int nw   = gridDim.x * (blockDim.x >> 6);
    const float w2v = w2[lane];
    const bool is64 = flag ? (*flag != 0) : false;
    const int* ts32 = (const int*)ts;
    const long long* ts64 = (const long long*)ts;

    for (int e = gw; e < n_edges; e += nw) {
        long long s, d;
        if (is64) { s = ts64[2 * e]; d = ts64[2 * e + 1]; }
        else      { s = ts32[2 * e]; d = ts32[2 * e + 1]; }
        float a = P[s * 128 + lane];
        float b = P[d * 128 + 64 + lane];
        float h = a + b;
        h = h > 0.0f ? h : 0.0f;
        float v = h * w2v;
#pragma unroll
        for (int off = 32; off > 0; off >>= 1) v += __shfl_xor(v, off);
        if (lane == 0) out[e] = v;
    }
}

// ---------------------------------------------------------------------------
// Fallback (only if ws too small for P): fused gather + MLP, wave per edge.
__global__ void __launch_bounds__(256)
direct_kernel(const float* __restrict__ emb, const void* __restrict__ ts,
              const int* __restrict__ flag, const float* __restrict__ w1,
              const float* __restrict__ b1, const float* __restrict__ w2,
              float* __restrict__ out, int n_edges) {
    const int lane = threadIdx.x & 63;
    const int gw   = blockIdx.x * (blockDim.x >> 6) + (threadIdx.x >> 6);
    const int nw   = gridDim.x * (blockDim.x >> 6);
    const float w2v  = w2[lane];
    const float bias = b1[lane];
    const bool is64 = flag ? (*flag != 0) : false;
    const int* ts32 = (const int*)ts;
    const long long* ts64 = (const long long*)ts;

    for (int e = gw; e < n_edges; e += nw) {
        long long s, d;
        if (is64) { s = ts64[2 * e]; d = ts64[2 * e + 1]; }
        else      { s = ts32[2 * e]; d = ts32[2 * e + 1]; }
        const float4* s4 = reinterpret_cast<const float4*>(emb + s * D_FEAT);
        const float4* d4 = reinterpret_cast<const float4*>(emb + d * D_FEAT);
        float acc = bias;
#pragma unroll
        for (int k4 = 0; k4 < 32; ++k4) {
            float4 r = s4[k4];
            acc += r.x * w1[(4 * k4 + 0) * 64 + lane];
            acc += r.y * w1[(4 * k4 + 1) * 64 + lane];
            acc += r.z * w1[(4 * k4 + 2) * 64 + lane];
            acc += r.w * w1[(4 * k4 + 3) * 64 + lane];
        }
#pragma unroll
        for (int k4 = 0; k4 < 32; ++k4) {
            float4 r = d4[k4];
            acc += r.x * w1[(128 + 4 * k4 + 0) * 64 + lane];
            acc += r.y * w1[(128 + 4 * k4 + 1) * 64 + lane];
            acc += r.z * w1[(128 + 4 * k4 + 2) * 64 + lane];
            acc += r.w * w1[(128 + 4 * k4 + 3) * 64 + lane];
        }
        float h = acc > 0.0f ? acc : 0.0f;
        float v = h * w2v;
#pragma unroll
        for (int off = 32; off > 0; off >>= 1) v += __shfl_xor(v, off);
        if (lane == 0) out[e] = v;
    }
}

// ---------------------------------------------------------------------------
extern "C" void kernel_launch(void* const* d_in, const int* in_sizes, int n_in,
                              void* d_out, int out_size, void* d_ws, size_t ws_size,
                              hipStream_t stream) {
    const float* emb = (const float*)d_in[0];
    const void*  ts  = d_in[1];
    const float* w1  = (const float*)d_in[2];
    const float* b1  = (const float*)d_in[3];
    const float* w2  = (const float*)d_in[4];
    float* out = (float*)d_out;

    const int n_nodes = in_sizes[0] / D_FEAT;   // 100000
    const int n_edges = in_sizes[1] / 2;        // 300000

    const size_t p_offset = 256;
    const size_t p_bytes  = (size_t)n_nodes * 128 * sizeof(float);
    const bool have_flag = ws_size >= sizeof(int);
    int* flag = have_flag ? (int*)d_ws : nullptr;

    if (have_flag) {
        detect_idx_kernel<<<1, 64, 0, stream>>>((const int*)ts, flag);
    }

    if (ws_size >= p_offset + p_bytes) {
        float* P = (float*)((char*)d_ws + p_offset);
        const int nblocks = (n_nodes + 127) / 128;
        precompute_kernel<<<nblocks, 256, 0, stream>>>(emb, w1, b1, P, n_nodes);
        edge_kernel<<<2048, 256, 0, stream>>>(P, ts, flag, w2, out, n_edges);
    } else {
        direct_kernel<<<2048, 256, 0, stream>>>(emb, ts, flag, w1, b1, w2, out, n_edges);
    }
}

// Round 3
// 48.058 us; speedup vs baseline: 7.9166x; 1.9963x over previous
//
#include <hip/hip_runtime.h>
#include <hip/hip_bf16.h>

// out[e] = relu(concat(emb[src], emb[dst]) @ w1 + b1) @ w2
// Restructure: P[n][j]    = emb[n] . w1[0:128, j]  + b1[j]   (j < 64)
//              P[n][64+j] = emb[n] . w1[128:256, j]          (j < 64)
// out[e] = sum_j relu(P[src][j] + P[dst][64+j]) * w2[j]
// P computed with bf16 MFMA (16x16x32), stored bf16. Error budget ~0.05 vs
// threshold 0.1256.

#define D_FEAT 128
#define HIDDEN 64

typedef __attribute__((ext_vector_type(8))) short v8s;   // 8 bf16 (4 VGPRs)
typedef __attribute__((ext_vector_type(4))) float f32x4; // 4 f32

__device__ inline unsigned short f2bf(float f) {
    unsigned u = __builtin_bit_cast(unsigned, f);
    unsigned r = (u + 0x7FFFu + ((u >> 16) & 1u)) >> 16;
    return (unsigned short)r;
}
__device__ inline float bf2f(unsigned short u) {
    return __builtin_bit_cast(float, (unsigned)u << 16);
}

// ---------------------------------------------------------------------------
// int64-vs-int32 index detection (odd int32 words all zero => int64 LE).
__global__ void detect_idx_kernel(const int* __restrict__ ts32, int* __restrict__ flag) {
    if (threadIdx.x == 0 && blockIdx.x == 0) {
        int is64 = 1;
        for (int i = 1; i < 64; i += 2)
            if (ts32[i] != 0) { is64 = 0; break; }
        *flag = is64;
    }
}

// ---------------------------------------------------------------------------
// Build Bt (w_eff transposed, bf16, XOR-swizzled) in workspace.
// Logical Bt[c][k] = w_eff[k][c], c,k in [0,128). Element index:
//   idx = (c*128 + k) ^ ((c&7)<<3)     (byte-level: ^ ((c&7)<<4))
// One 16B LDS slot per 8 k; swizzle spreads the 16 same-k columns over 8
// bank-quads so full-wave ds_read_b128 is phase-conflict-free.
__global__ void prep_bt_kernel(const float* __restrict__ w1, unsigned short* __restrict__ bt) {
    const int t = threadIdx.x;          // 0..255 == w1 row
    const float* src = w1 + (size_t)t * 64;   // w1[t][0..63]
    const int half = t >> 7;            // 0: cols 0..63, 1: cols 64..127
    const int k = t & 127;
#pragma unroll 4
    for (int j = 0; j < 64; ++j) {
        const int c = half * 64 + j;
        const int idx = (c * 128 + k) ^ ((c & 7) << 3);
        bt[idx] = f2bf(src[j]);
    }
}

// ---------------------------------------------------------------------------
// Precompute P (n_nodes x 128, bf16) = bf16(emb) @ bf16(w_eff) (+bias cols<64).
// Block: 256 thr = 4 waves, each wave one 16-row m-tile (block = 64 rows).
// A-fragments straight from global (coalesced 16x128B per load); B from LDS.
// k-permutation inside a fragment cancels: A and B use the same
// (lane>>4, j) -> k = 8*(lane>>4)+j mapping.
__global__ void __launch_bounds__(256)
precompute_kernel(const float* __restrict__ emb, const unsigned short* __restrict__ bt_ws,
                  const float* __restrict__ b1, unsigned short* __restrict__ P,
                  int n_nodes) {
    __shared__ unsigned short bt[16384];   // 32 KiB
    const int t = threadIdx.x;

    // stage swizzled Bt linearly: 8 x 16B per thread
#pragma unroll
    for (int i = 0; i < 8; ++i) {
        const int off = i * 4096 + t * 16;
        *reinterpret_cast<f32x4*>(reinterpret_cast<char*>(bt) + off) =
            *reinterpret_cast<const f32x4*>(reinterpret_cast<const char*>(bt_ws) + off);
    }
    __syncthreads();

    const int lane = t & 63;
    const int wid  = t >> 6;
    const int sub  = lane & 15;   // row (A) / col (B,D) within tile
    const int g    = lane >> 4;   // k-group
    const int m0   = blockIdx.x * 64 + wid * 16;

    int arow = m0 + sub;
    if (arow >= n_nodes) arow = n_nodes - 1;
    const float* aptr = emb + (size_t)arow * D_FEAT + g * 8;

    f32x4 acc[8];
#pragma unroll
    for (int nj = 0; nj < 8; ++nj) acc[nj] = (f32x4){0.f, 0.f, 0.f, 0.f};

#pragma unroll
    for (int ks = 0; ks < 4; ++ks) {
        const int k0 = ks * 32;
        // A: 8 consecutive f32 at emb[arow][k0 + 8g .. +7]
        const float4 a0 = *reinterpret_cast<const float4*>(aptr + k0);
        const float4 a1 = *reinterpret_cast<const float4*>(aptr + k0 + 4);
        v8s af;
        af[0] = (short)f2bf(a0.x); af[1] = (short)f2bf(a0.y);
        af[2] = (short)f2bf(a0.z); af[3] = (short)f2bf(a0.w);
        af[4] = (short)f2bf(a1.x); af[5] = (short)f2bf(a1.y);
        af[6] = (short)f2bf(a1.z); af[7] = (short)f2bf(a1.w);
#pragma unroll
        for (int nj = 0; nj < 8; ++nj) {
            const int c = nj * 16 + sub;
            const int eidx = ((c * 128) + (k0 + g * 8)) ^ ((c & 7) << 3);
            const v8s bf = *reinterpret_cast<const v8s*>(&bt[eidx]);
            acc[nj] = __builtin_amdgcn_mfma_f32_16x16x32_bf16(af, bf, acc[nj], 0, 0, 0);
        }
    }

    // epilogue: bias on cols<64, store bf16.  D: row=g*4+reg, col=sub (per tile)
    float bias[8];
#pragma unroll
    for (int nj = 0; nj < 8; ++nj) {
        const int c = nj * 16 + sub;
        bias[nj] = (c < HIDDEN) ? b1[c] : 0.0f;
    }
#pragma unroll
    for (int nj = 0; nj < 8; ++nj) {
        const int c = nj * 16 + sub;
#pragma unroll
        for (int reg = 0; reg < 4; ++reg) {
            const int r = m0 + g * 4 + reg;
            if (r < n_nodes)
                P[(size_t)r * 128 + c] = f2bf(acc[nj][reg] + bias[nj]);
        }
    }
}

// ---------------------------------------------------------------------------
// Edge pass: 16 lanes per edge. Lane sub=lane&15 covers hidden units
// 4*sub..4*sub+3 via one 8B bf16x4 load per operand half. 4 edges per wave.
__global__ void __launch_bounds__(256)
edge_kernel(const unsigned short* __restrict__ P, const void* __restrict__ ts,
            const int* __restrict__ flag, const float* __restrict__ w2,
            float* __restrict__ out, int n_edges) {
    const int lane = threadIdx.x & 63;
    const int wid  = threadIdx.x >> 6;
    const int sub  = lane & 15;
    const int grp  = lane >> 4;
    const int gw   = blockIdx.x * 4 + wid;
    const int nw   = gridDim.x * 4;

    const float4 w2v = *reinterpret_cast<const float4*>(w2 + sub * 4);
    const bool is64 = (*flag != 0);
    const int* ts32 = (const int*)ts;
    const long long* ts64 = (const long long*)ts;

    for (int e = gw * 4 + grp; e < n_edges; e += nw * 4) {
        long long s, d;
        if (is64) { s = ts64[2 * e]; d = ts64[2 * e + 1]; }
        else      { s = ts32[2 * e]; d = ts32[2 * e + 1]; }
        const ushort4 a = *reinterpret_cast<const ushort4*>(P + (size_t)s * 128 + sub * 4);
        const ushort4 b = *reinterpret_cast<const ushort4*>(P + (size_t)d * 128 + 64 + sub * 4);
        float h0 = bf2f(a.x) + bf2f(b.x);
        float h1 = bf2f(a.y) + bf2f(b.y);
        float h2 = bf2f(a.z) + bf2f(b.z);
        float h3 = bf2f(a.w) + bf2f(b.w);
        h0 = h0 > 0.f ? h0 : 0.f; h1 = h1 > 0.f ? h1 : 0.f;
        h2 = h2 > 0.f ? h2 : 0.f; h3 = h3 > 0.f ? h3 : 0.f;
        float v = h0 * w2v.x + h1 * w2v.y + h2 * w2v.z + h3 * w2v.w;
#pragma unroll
        for (int off = 8; off > 0; off >>= 1) v += __shfl_xor(v, off);
        if (sub == 0) out[e] = v;
    }
}

// ---------------------------------------------------------------------------
// Fallback (ws too small): fused gather + f32 MLP, wave per edge.
__global__ void __launch_bounds__(256)
direct_kernel(const float* __restrict__ emb, const void* __restrict__ ts,
              const int* __restrict__ flag, const float* __restrict__ w1,
              const float* __restrict__ b1, const float* __restrict__ w2,
              float* __restrict__ out, int n_edges) {
    const int lane = threadIdx.x & 63;
    const int gw   = blockIdx.x * (blockDim.x >> 6) + (threadIdx.x >> 6);
    const int nw   = gridDim.x * (blockDim.x >> 6);
    const float w2v  = w2[lane];
    const float bias = b1[lane];
    const bool is64 = flag ? (*flag != 0) : false;
    const int* ts32 = (const int*)ts;
    const long long* ts64 = (const long long*)ts;

    for (int e = gw; e < n_edges; e += nw) {
        long long s, d;
        if (is64) { s = ts64[2 * e]; d = ts64[2 * e + 1]; }
        else      { s = ts32[2 * e]; d = ts32[2 * e + 1]; }
        const float4* s4 = reinterpret_cast<const float4*>(emb + s * D_FEAT);
        const float4* d4 = reinterpret_cast<const float4*>(emb + d * D_FEAT);
        float acc = bias;
#pragma unroll
        for (int k4 = 0; k4 < 32; ++k4) {
            float4 r = s4[k4];
            acc += r.x * w1[(4 * k4 + 0) * 64 + lane];
            acc += r.y * w1[(4 * k4 + 1) * 64 + lane];
            acc += r.z * w1[(4 * k4 + 2) * 64 + lane];
            acc += r.w * w1[(4 * k4 + 3) * 64 + lane];
        }
#pragma unroll
        for (int k4 = 0; k4 < 32; ++k4) {
            float4 r = d4[k4];
            acc += r.x * w1[(128 + 4 * k4 + 0) * 64 + lane];
            acc += r.y * w1[(128 + 4 * k4 + 1) * 64 + lane];
            acc += r.z * w1[(128 + 4 * k4 + 2) * 64 + lane];
            acc += r.w * w1[(128 + 4 * k4 + 3) * 64 + lane];
        }
        float h = acc > 0.0f ? acc : 0.0f;
        float v = h * w2v;
#pragma unroll
        for (int off = 32; off > 0; off >>= 1) v += __shfl_xor(v, off);
        if (lane == 0) out[e] = v;
    }
}

// ---------------------------------------------------------------------------
extern "C" void kernel_launch(void* const* d_in, const int* in_sizes, int n_in,
                              void* d_out, int out_size, void* d_ws, size_t ws_size,
                              hipStream_t stream) {
    const float* emb = (const float*)d_in[0];
    const void*  ts  = d_in[1];
    const float* w1  = (const float*)d_in[2];
    const float* b1  = (const float*)d_in[3];
    const float* w2  = (const float*)d_in[4];
    float* out = (float*)d_out;

    const int n_nodes = in_sizes[0] / D_FEAT;   // 100000
    const int n_edges = in_sizes[1] / 2;        // 300000

    // ws layout: [0..4) flag | [4096..36864) Bt bf16 | [36864..) P bf16
    const size_t bt_off = 4096;
    const size_t p_off  = 36864;
    const size_t p_bytes = (size_t)n_nodes * 128 * sizeof(unsigned short);

    if (ws_size >= p_off + p_bytes) {
        int* flag = (int*)d_ws;
        unsigned short* bt = (unsigned short*)((char*)d_ws + bt_off);
        unsigned short* P  = (unsigned short*)((char*)d_ws + p_off);

        detect_idx_kernel<<<1, 64, 0, stream>>>((const int*)ts, flag);
        prep_bt_kernel<<<1, 256, 0, stream>>>(w1, bt);
        const int nblocks = (n_nodes + 63) / 64;
        precompute_kernel<<<nblocks, 256, 0, stream>>>(emb, bt, b1, P, n_nodes);
        edge_kernel<<<2048, 256, 0, stream>>>(P, ts, flag, w2, out, n_edges);
    } else if (ws_size >= sizeof(int)) {
        int* flag = (int*)d_ws;
        detect_idx_kernel<<<1, 64, 0, stream>>>((const int*)ts, flag);
        direct_kernel<<<2048, 256, 0, stream>>>(emb, ts, flag, w1, b1, w2, out, n_edges);
    }
}

// Round 4
// 45.680 us; speedup vs baseline: 8.3286x; 1.0521x over previous
//
#include <hip/hip_runtime.h>
#include <hip/hip_bf16.h>

// out[e] = relu(concat(emb[src], emb[dst]) @ w1 + b1) @ w2
// Restructure: P[n][j]    = emb[n] . w1[0:128, j]  + b1[j]   (j < 64)
//              P[n][64+j] = emb[n] . w1[128:256, j]          (j < 64)
// out[e] = sum_j relu(P[src][j] + P[dst][64+j]) * w2[j]
// P computed with bf16 MFMA (16x16x32), stored bf16 (error ~0.03 vs thr 0.126).
// MFMA operands SWAPPED (D = (emb@W)^T): lane holds 4 consecutive P-cols of
// one node -> 8B ushort4 stores instead of 2B scalar stores.

#define D_FEAT 128
#define HIDDEN 64

typedef __attribute__((ext_vector_type(8))) short v8s;   // 8 bf16 (4 VGPRs)
typedef __attribute__((ext_vector_type(4))) float f32x4; // 4 f32

__device__ inline unsigned short f2bf(float f) {
    unsigned u = __builtin_bit_cast(unsigned, f);
    unsigned r = (u + 0x7FFFu + ((u >> 16) & 1u)) >> 16;
    return (unsigned short)r;
}
__device__ inline float bf2f(unsigned short u) {
    return __builtin_bit_cast(float, (unsigned)u << 16);
}

// Inline int64-vs-int32 detection: for int64 (LE) data with idx < 2^31, every
// odd int32 word is 0. For int32 data, odd words are real indices (all-zero
// across 64 words has prob ~1e-160). One load + ballot per wave.
__device__ inline bool detect_is64(const int* ts32, int lane) {
    int probe = ts32[2 * lane + 1];
    return __ballot(probe != 0) == 0ULL;
}

// ---------------------------------------------------------------------------
// Precompute P (n_nodes x 128, bf16). Block: 256 thr = 4 waves; each wave
// covers 2 node-tiles of 16 (block = 128 nodes). Bt (w_eff^T, bf16,
// XOR-swizzled) built in LDS per block from w1. B-fragments shared across the
// wave's 2 tiles; A straight from global (16 rows x 32B, two dwordx4 each).
__global__ void __launch_bounds__(256)
precompute_kernel(const float* __restrict__ emb, const float* __restrict__ w1,
                  const float* __restrict__ b1, unsigned short* __restrict__ P,
                  int n_nodes) {
    __shared__ unsigned short bt[16384];   // Bt[c][k] at (c*128+k)^((c&7)<<3)
    const int t = threadIdx.x;

    // ---- build swizzled Bt from w1 (256x64 f32): thread t owns w1 row t.
    // half==0 (t<128): w_eff[k=t][c=j],      half==1: w_eff[k=t-128][c=64+j].
    {
        const int k    = t & 127;
        const int half = t >> 7;
        const float4* src = reinterpret_cast<const float4*>(w1 + (size_t)t * 64);
#pragma unroll
        for (int j4 = 0; j4 < 16; ++j4) {
            const float4 v = src[j4];
            const int cb = half * 64 + j4 * 4;
            bt[((cb + 0) * 128 + k) ^ (((cb + 0) & 7) << 3)] = f2bf(v.x);
            bt[((cb + 1) * 128 + k) ^ (((cb + 1) & 7) << 3)] = f2bf(v.y);
            bt[((cb + 2) * 128 + k) ^ (((cb + 2) & 7) << 3)] = f2bf(v.z);
            bt[((cb + 3) * 128 + k) ^ (((cb + 3) & 7) << 3)] = f2bf(v.w);
        }
    }
    __syncthreads();

    const int lane = t & 63;
    const int wid  = t >> 6;
    const int sub  = lane & 15;   // node within tile / Bt row c within c-tile
    const int g    = lane >> 4;   // k-group
    const int base = blockIdx.x * 128 + wid * 32;   // wave's 2x16 nodes

    const float* aptr[2];
#pragma unroll
    for (int tl = 0; tl < 2; ++tl) {
        int arow = base + tl * 16 + sub;
        if (arow >= n_nodes) arow = n_nodes - 1;
        aptr[tl] = emb + (size_t)arow * D_FEAT + g * 8;
    }

    f32x4 acc[2][8];
#pragma unroll
    for (int tl = 0; tl < 2; ++tl)
#pragma unroll
        for (int nj = 0; nj < 8; ++nj) acc[tl][nj] = (f32x4){0.f, 0.f, 0.f, 0.f};

#pragma unroll
    for (int ks = 0; ks < 4; ++ks) {
        const int k0 = ks * 32;
        v8s af[2];
#pragma unroll
        for (int tl = 0; tl < 2; ++tl) {
            const float4 a0 = *reinterpret_cast<const float4*>(aptr[tl] + k0);
            const float4 a1 = *reinterpret_cast<const float4*>(aptr[tl] + k0 + 4);
            af[tl][0] = (short)f2bf(a0.x); af[tl][1] = (short)f2bf(a0.y);
            af[tl][2] = (short)f2bf(a0.z); af[tl][3] = (short)f2bf(a0.w);
            af[tl][4] = (short)f2bf(a1.x); af[tl][5] = (short)f2bf(a1.y);
            af[tl][6] = (short)f2bf(a1.z); af[tl][7] = (short)f2bf(a1.w);
        }
#pragma unroll
        for (int nj = 0; nj < 8; ++nj) {
            const int c = nj * 16 + sub;
            const int eidx = (c * 128 + k0 + g * 8) ^ ((c & 7) << 3);
            const v8s bf = *reinterpret_cast<const v8s*>(&bt[eidx]);
            // swapped: D = W^T . emb^T ; D[c][node], col=node=sub,
            // row = c_local = g*4+reg
            acc[0][nj] = __builtin_amdgcn_mfma_f32_16x16x32_bf16(bf, af[0], acc[0][nj], 0, 0, 0);
            acc[1][nj] = __builtin_amdgcn_mfma_f32_16x16x32_bf16(bf, af[1], acc[1][nj], 0, 0, 0);
        }
    }

    // ---- epilogue: lane holds P cols nj*16+g*4..+3 for node base+tl*16+sub
    float4 bias[4];   // cols < 64 only (nj < 4)
#pragma unroll
    for (int nj = 0; nj < 4; ++nj)
        bias[nj] = *reinterpret_cast<const float4*>(b1 + nj * 16 + g * 4);

#pragma unroll
    for (int tl = 0; tl < 2; ++tl) {
        const int node = base + tl * 16 + sub;
        if (node < n_nodes) {
#pragma unroll
            for (int nj = 0; nj < 8; ++nj) {
                float b0 = 0.f, b1v = 0.f, b2 = 0.f, b3 = 0.f;
                if (nj < 4) { b0 = bias[nj].x; b1v = bias[nj].y;
                              b2 = bias[nj].z; b3 = bias[nj].w; }
                ushort4 o;
                o.x = f2bf(acc[tl][nj][0] + b0);
                o.y = f2bf(acc[tl][nj][1] + b1v);
                o.z = f2bf(acc[tl][nj][2] + b2);
                o.w = f2bf(acc[tl][nj][3] + b3);
                *reinterpret_cast<ushort4*>(P + (size_t)node * 128 + nj * 16 + g * 4) = o;
            }
        }
    }
}

// ---------------------------------------------------------------------------
// Edge pass: 16 lanes per edge, 4 edges per wave. 8B bf16x4 loads per half.
__global__ void __launch_bounds__(256)
edge_kernel(const unsigned short* __restrict__ P, const void* __restrict__ ts,
            const float* __restrict__ w2, float* __restrict__ out, int n_edges) {
    const int lane = threadIdx.x & 63;
    const int wid  = threadIdx.x >> 6;
    const int sub  = lane & 15;
    const int grp  = lane >> 4;
    const int gw   = blockIdx.x * 4 + wid;
    const int nw   = gridDim.x * 4;

    const int* ts32 = (const int*)ts;
    const long long* ts64 = (const long long*)ts;
    const bool is64 = detect_is64(ts32, lane);

    const float4 w2v = *reinterpret_cast<const float4*>(w2 + sub * 4);

    for (int e = gw * 4 + grp; e < n_edges; e += nw * 4) {
        long long s, d;
        if (is64) { s = ts64[2 * e]; d = ts64[2 * e + 1]; }
        else      { s = ts32[2 * e]; d = ts32[2 * e + 1]; }
        const ushort4 a = *reinterpret_cast<const ushort4*>(P + (size_t)s * 128 + sub * 4);
        const ushort4 b = *reinterpret_cast<const ushort4*>(P + (size_t)d * 128 + 64 + sub * 4);
        float h0 = bf2f(a.x) + bf2f(b.x);
        float h1 = bf2f(a.y) + bf2f(b.y);
        float h2 = bf2f(a.z) + bf2f(b.z);
        float h3 = bf2f(a.w) + bf2f(b.w);
        h0 = h0 > 0.f ? h0 : 0.f; h1 = h1 > 0.f ? h1 : 0.f;
        h2 = h2 > 0.f ? h2 : 0.f; h3 = h3 > 0.f ? h3 : 0.f;
        float v = h0 * w2v.x + h1 * w2v.y + h2 * w2v.z + h3 * w2v.w;
#pragma unroll
        for (int off = 8; off > 0; off >>= 1) v += __shfl_xor(v, off);
        if (sub == 0) out[e] = v;
    }
}

// ---------------------------------------------------------------------------
// Fallback (ws too small for P): fused gather + f32 MLP, wave per edge.
__global__ void __launch_bounds__(256)
direct_kernel(const float* __restrict__ emb, const void* __restrict__ ts,
              const float* __restrict__ w1, const float* __restrict__ b1,
              const float* __restrict__ w2, float* __restrict__ out, int n_edges) {
    const int lane = threadIdx.x & 63;
    const int gw   = blockIdx.x * (blockDim.x >> 6) + (threadIdx.x >> 6);
    const int nw   = gridDim.x * (blockDim.x >> 6);
    const float w2v  = w2[lane];
    const float bias = b1[lane];
    const int* ts32 = (const int*)ts;
    const long long* ts64 = (const long long*)ts;
    const bool is64 = detect_is64(ts32, lane);

    for (int e = gw; e < n_edges; e += nw) {
        long long s, d;
        if (is64) { s = ts64[2 * e]; d = ts64[2 * e + 1]; }
        else      { s = ts32[2 * e]; d = ts32[2 * e + 1]; }
        const float4* s4 = reinterpret_cast<const float4*>(emb + s * D_FEAT);
        const float4* d4 = reinterpret_cast<const float4*>(emb + d * D_FEAT);
        float acc = bias;
#pragma unroll
        for (int k4 = 0; k4 < 32; ++k4) {
            float4 r = s4[k4];
            acc += r.x * w1[(4 * k4 + 0) * 64 + lane];
            acc += r.y * w1[(4 * k4 + 1) * 64 + lane];
            acc += r.z * w1[(4 * k4 + 2) * 64 + lane];
            acc += r.w * w1[(4 * k4 + 3) * 64 + lane];
        }
#pragma unroll
        for (int k4 = 0; k4 < 32; ++k4) {
            float4 r = d4[k4];
            acc += r.x * w1[(128 + 4 * k4 + 0) * 64 + lane];
            acc += r.y * w1[(128 + 4 * k4 + 1) * 64 + lane];
            acc += r.z * w1[(128 + 4 * k4 + 2) * 64 + lane];
            acc += r.w * w1[(128 + 4 * k4 + 3) * 64 + lane];
        }
        float h = acc > 0.0f ? acc : 0.0f;
        float v = h * w2v;
#pragma unroll
        for (int off = 32; off > 0; off >>= 1) v += __shfl_xor(v, off);
        if (lane == 0) out[e] = v;
    }
}

// ---------------------------------------------------------------------------
extern "C" void kernel_launch(void* const* d_in, const int* in_sizes, int n_in,
                              void* d_out, int out_size, void* d_ws, size_t ws_size,
                              hipStream_t stream) {
    const float* emb = (const float*)d_in[0];
    const void*  ts  = d_in[1];
    const float* w1  = (const float*)d_in[2];
    const float* b1  = (const float*)d_in[3];
    const float* w2  = (const float*)d_in[4];
    float* out = (float*)d_out;

    const int n_nodes = in_sizes[0] / D_FEAT;   // 100000
    const int n_edges = in_sizes[1] / 2;        // 300000

    const size_t p_bytes = (size_t)n_nodes * 128 * sizeof(unsigned short);

    if (ws_size >= p_bytes) {
        unsigned short* P = (unsigned short*)d_ws;
        const int nblocks = (n_nodes + 127) / 128;
        precompute_kernel<<<nblocks, 256, 0, stream>>>(emb, w1, b1, P, n_nodes);
        edge_kernel<<<2048, 256, 0, stream>>>(P, ts, w2, out, n_edges);
    } else {
        direct_kernel<<<2048, 256, 0, stream>>>(emb, ts, w1, b1, w2, out, n_edges);
    }
}